// Round 4
// baseline (866.028 us; speedup 1.0000x reference)
//
#include <hip/hip_runtime.h>
#include <hip/hip_bf16.h>

typedef __attribute__((ext_vector_type(8))) short short8;
typedef __attribute__((ext_vector_type(4))) float f32x4;
typedef __attribute__((ext_vector_type(2))) float f32x2;

#define NN 100000
#define NE 3200000
#define NTILES (NE / 16)
#define NBLK_SCAN 391            // ceil(NN/256)
#define NWAVES 8192              // 2048 blocks x 4 waves
#define KTILES 25                // ceil(NTILES/NWAVES)

__device__ __forceinline__ short f2bf(float f) {
  __hip_bfloat16 h = __float2bfloat16(f);
  return *reinterpret_cast<short*>(&h);
}

__device__ __forceinline__ f32x4 mfma16(short8 a, short8 b, f32x4 c) {
  return __builtin_amdgcn_mfma_f32_16x16x32_bf16(a, b, c, 0, 0, 0);
}

// ---------------- counting sort by dst ----------------
__global__ void __launch_bounds__(256) k_hist(const int* __restrict__ dst,
                                              int* __restrict__ counts) {
  int i = blockIdx.x * 256 + threadIdx.x;
  if (i < NE) atomicAdd(&counts[dst[i]], 1);
}

__global__ void __launch_bounds__(256) k_scan1(const int* __restrict__ counts,
                                               int* __restrict__ loff,
                                               int* __restrict__ blocksum) {
  __shared__ int sm[256];
  int t = threadIdx.x;
  int i = blockIdx.x * 256 + t;
  int v = (i < NN) ? counts[i] : 0;
  sm[t] = v; __syncthreads();
  for (int off = 1; off < 256; off <<= 1) {
    int x = (t >= off) ? sm[t - off] : 0;
    __syncthreads();
    sm[t] += x;
    __syncthreads();
  }
  if (i < NN) loff[i] = sm[t] - v;          // exclusive within block
  if (t == 255) blocksum[blockIdx.x] = sm[255];
}

__global__ void __launch_bounds__(512) k_scan2(const int* __restrict__ blocksum,
                                               int* __restrict__ blockpref) {
  __shared__ int sm[512];
  int t = threadIdx.x;
  int v = (t < NBLK_SCAN) ? blocksum[t] : 0;
  sm[t] = v; __syncthreads();
  for (int off = 1; off < 512; off <<= 1) {
    int x = (t >= off) ? sm[t - off] : 0;
    __syncthreads();
    sm[t] += x;
    __syncthreads();
  }
  if (t < NBLK_SCAN) blockpref[t] = sm[t] - v;  // exclusive
}

__global__ void __launch_bounds__(256) k_scan3(const int* __restrict__ loff,
                                               const int* __restrict__ blockpref,
                                               int* __restrict__ cursor) {
  int i = blockIdx.x * 256 + threadIdx.x;
  if (i < NN) cursor[i] = loff[i] + blockpref[blockIdx.x];
}

__global__ void __launch_bounds__(256) k_scatter(const int* __restrict__ dst,
                                                 int* __restrict__ cursor,
                                                 int* __restrict__ sorted) {
  int i = blockIdx.x * 256 + threadIdx.x;
  if (i < NE) {
    int p = atomicAdd(&cursor[dst[i]], 1);
    sorted[p] = i;
  }
}

// ---------------- main fused kernel (dst-sorted order) ----------------
// Per-wave tile: 16 edges (dst-sorted). A-frag: lane holds row (l&15),
// k=(l>>4)*8+j. B-frag: lane holds col (l&15). D: row=(l>>4)*4+r, col=(l&15).
// Each wave owns a contiguous run of KTILES tiles; msg rows are segment-
// reduced across tiles (dst-sorted => runs adjacent) and flushed with one
// 32-lane atomic per run boundary.
__global__ void __launch_bounds__(256) mpn_main(
    const float* __restrict__ x_node,
    const float* __restrict__ x_edge,
    const int*   __restrict__ srcp,
    const int*   __restrict__ dstp,
    const int*   __restrict__ bmp,
    const int*   __restrict__ sorted,
    const float* __restrict__ Wn1, const float* __restrict__ bn1,
    const float* __restrict__ Wn2, const float* __restrict__ bn2,
    const float* __restrict__ We1, const float* __restrict__ be1,
    const float* __restrict__ We2, const float* __restrict__ be2,
    float* __restrict__ out_nm,
    float* __restrict__ out_em)
{
  __shared__ short lds_h1[4][16][40];
  __shared__ float lds_em[4][16][12];
  __shared__ short lds_h2[4][16][72];
  __shared__ float lds_ms[4][16][33];
  __shared__ int   lds_eid[4][16];
  __shared__ int   lds_dst[4][16];

  const int tid  = threadIdx.x;
  const int wid  = tid >> 6;
  const int lane = tid & 63;
  const int col  = lane & 15;
  const int kg   = lane >> 4;

  for (int i = lane; i < 16 * 12; i += 64)
    ((float*)lds_em[wid])[i] = 0.f;

  // ---- resident bf16 weight B-fragments (one-time) ----
  auto ldb = [&](const float* W, int K, int N, int kc, int nt) {
    int n  = nt * 16 + col;
    int k0 = kc * 32 + kg * 8;
    short8 r;
#pragma unroll
    for (int j = 0; j < 8; ++j) {
      int k = k0 + j;
      float v = (k < K && n < N) ? W[k * N + n] : 0.f;
      r[j] = f2bf(v);
    }
    return r;
  };

  short8 B_e1[3][2], B_n1[2][4], B_n2[2][2], B_e2;
#pragma unroll
  for (int kc = 0; kc < 3; ++kc)
#pragma unroll
    for (int nt = 0; nt < 2; ++nt) B_e1[kc][nt] = ldb(We1, 70, 32, kc, nt);
  B_e2 = ldb(We2, 32, 6, 0, 0);
#pragma unroll
  for (int kc = 0; kc < 2; ++kc)
#pragma unroll
    for (int nt = 0; nt < 4; ++nt) B_n1[kc][nt] = ldb(Wn1, 38, 64, kc, nt);
#pragma unroll
  for (int kc = 0; kc < 2; ++kc)
#pragma unroll
    for (int nt = 0; nt < 2; ++nt) B_n2[kc][nt] = ldb(Wn2, 64, 32, kc, nt);

  float bias_e1[2], bias_n1[4], bias_n2[2], bias_e2;
  bias_e1[0] = be1[col];      bias_e1[1] = be1[16 + col];
  bias_e2    = (col < 6) ? be2[col] : 0.f;
#pragma unroll
  for (int nt = 0; nt < 4; ++nt) bias_n1[nt] = bn1[nt * 16 + col];
  bias_n2[0] = bn2[col];      bias_n2[1] = bn2[16 + col];

  const int gw = blockIdx.x * 4 + wid;
  const int t0 = gw * KTILES;
  const int tE = min(t0 + KTILES, NTILES);
  if (t0 >= NTILES) return;

  auto ldidx = [&](int t, int& e, int& s, int& d, int& b) {
    e = sorted[t * 16 + col];
    s = srcp[e]; d = dstp[e]; b = bmp[e];
  };
  auto gather = [&](int e, int s, int d,
                    f32x4& g0, f32x4& g1, f32x4& g2, f32x4& g3,
                    f32x2& e0, f32x2& e1, f32x2& e2) {
    const float* ps = x_node + (long)s * 32 + kg * 8;
    const float* pd = x_node + (long)d * 32 + kg * 8;
    g0 = *(const f32x4*)ps; g1 = *(const f32x4*)(ps + 4);
    g2 = *(const f32x4*)pd; g3 = *(const f32x4*)(pd + 4);
    if (kg == 0) {
      const float* pe = x_edge + (long)e * 6;
      e0 = *(const f32x2*)pe; e1 = *(const f32x2*)(pe + 2); e2 = *(const f32x2*)(pe + 4);
    }
  };

  // segmented-reduction state (lanes 0..31; col index = lane)
  float accL  = 0.f;
  int   curDst = -1;

  // ---------------- pipeline prologue ----------------
  int eI, sI, dI, bI;
  int tC = t0;
  ldidx(tC, eI, sI, dI, bI);
  f32x4 Rs0, Rs1, Rd0, Rd1; f32x2 Re0, Re1, Re2;
  gather(eI, sI, dI, Rs0, Rs1, Rd0, Rd1, Re0, Re1, Re2);
  int bR = bI, eR = eI, dR = dI;
  int tN = t0 + 1;
  { int tc = (tN < tE) ? tN : (tE - 1); ldidx(tc, eI, sI, dI, bI); }

  while (true) {
    f32x4 Ns0, Ns1, Nd0, Nd1; f32x2 Ne0, Ne1, Ne2;
    gather(eI, sI, dI, Ns0, Ns1, Nd0, Nd1, Ne0, Ne1, Ne2);
    int bN = bI, eN = eI, dN = dI;
    { int t2 = tN + 1; int tc = (t2 < tE) ? t2 : (tE - 1);
      ldidx(tc, eI, sI, dI, bI); }

    // ---- compute tile tC ----
    // publish per-row edge id + dst (row = col; kg==0 lanes hold them)
    if (kg == 0) { lds_eid[wid][col] = eR; lds_dst[wid][col] = dR; }

    short8 XS, XD;
#pragma unroll
    for (int j = 0; j < 4; ++j) {
      XS[j] = f2bf(Rs0[j]); XS[4 + j] = f2bf(Rs1[j]);
      XD[j] = f2bf(Rd0[j]); XD[4 + j] = f2bf(Rd1[j]);
    }
    short8 AE = {0, 0, 0, 0, 0, 0, 0, 0};
    if (kg == 0) {
      AE[0] = f2bf(Re0[0]); AE[1] = f2bf(Re0[1]);
      AE[2] = f2bf(Re1[0]); AE[3] = f2bf(Re1[1]);
      AE[4] = f2bf(Re2[0]); AE[5] = f2bf(Re2[1]);
    }
    const bool back = (bR != 0);
    short8 Aa = back ? XD : XS;
    short8 Ab = back ? XS : XD;

    // edge MLP layer 1
    f32x4 a0 = {bias_e1[0], bias_e1[0], bias_e1[0], bias_e1[0]};
    f32x4 a1 = {bias_e1[1], bias_e1[1], bias_e1[1], bias_e1[1]};
    a0 = mfma16(Aa, B_e1[0][0], a0);
    a0 = mfma16(Ab, B_e1[1][0], a0);
    a0 = mfma16(AE, B_e1[2][0], a0);
    a1 = mfma16(Aa, B_e1[0][1], a1);
    a1 = mfma16(Ab, B_e1[1][1], a1);
    a1 = mfma16(AE, B_e1[2][1], a1);

#pragma unroll
    for (int r = 0; r < 4; ++r) {
      lds_h1[wid][kg * 4 + r][col]      = f2bf(fmaxf(a0[r], 0.f));
      lds_h1[wid][kg * 4 + r][16 + col] = f2bf(fmaxf(a1[r], 0.f));
    }
    short8 Ah1 = *(const short8*)&lds_h1[wid][col][kg * 8];

    // edge MLP layer 2
    f32x4 ae2 = {bias_e2, bias_e2, bias_e2, bias_e2};
    ae2 = mfma16(Ah1, B_e2, ae2);

    if (col < 6) {
#pragma unroll
      for (int r = 0; r < 4; ++r) {
        int row = kg * 4 + r;
        float v = ae2[r];
        out_em[(long)lds_eid[wid][row] * 6 + col] = v;
        lds_em[wid][row][col] = v;
      }
    }
    short8 Aem = {0, 0, 0, 0, 0, 0, 0, 0};
    if (kg == 0) {
      f32x4 u0 = *(const f32x4*)&lds_em[wid][col][0];
      f32x4 u1 = *(const f32x4*)&lds_em[wid][col][4];
      Aem[0] = f2bf(u0[0]); Aem[1] = f2bf(u0[1]);
      Aem[2] = f2bf(u0[2]); Aem[3] = f2bf(u0[3]);
      Aem[4] = f2bf(u1[0]); Aem[5] = f2bf(u1[1]);
      Aem[6] = f2bf(u1[2]); Aem[7] = f2bf(u1[3]);
    }

    // node MLP layer 1
    f32x4 an[4];
#pragma unroll
    for (int nt = 0; nt < 4; ++nt) {
      an[nt] = (f32x4){bias_n1[nt], bias_n1[nt], bias_n1[nt], bias_n1[nt]};
      an[nt] = mfma16(XD,  B_n1[0][nt], an[nt]);
      an[nt] = mfma16(Aem, B_n1[1][nt], an[nt]);
    }
#pragma unroll
    for (int nt = 0; nt < 4; ++nt)
#pragma unroll
      for (int r = 0; r < 4; ++r)
        lds_h2[wid][kg * 4 + r][nt * 16 + col] = f2bf(fmaxf(an[nt][r], 0.f));
    short8 Ah2a = *(const short8*)&lds_h2[wid][col][kg * 8];
    short8 Ah2b = *(const short8*)&lds_h2[wid][col][32 + kg * 8];

    // node MLP layer 2
    f32x4 am0 = {bias_n2[0], bias_n2[0], bias_n2[0], bias_n2[0]};
    f32x4 am1 = {bias_n2[1], bias_n2[1], bias_n2[1], bias_n2[1]};
    am0 = mfma16(Ah2a, B_n2[0][0], am0);
    am0 = mfma16(Ah2b, B_n2[1][0], am0);
    am1 = mfma16(Ah2a, B_n2[0][1], am1);
    am1 = mfma16(Ah2b, B_n2[1][1], am1);

    // ---- segmented reduce + sparse atomic flush ----
#pragma unroll
    for (int r = 0; r < 4; ++r) {
      lds_ms[wid][kg * 4 + r][col]      = am0[r];
      lds_ms[wid][kg * 4 + r][16 + col] = am1[r];
    }
    if (lane < 32) {
      // rows are dst-sorted; branch is uniform across the 32 active lanes
#pragma unroll
      for (int r = 0; r < 16; ++r) {
        int   dr = lds_dst[wid][r];
        float v  = lds_ms[wid][r][lane];
        if (dr != curDst) {
          if (curDst >= 0)
            unsafeAtomicAdd(out_nm + (long)curDst * 32 + lane, accL);
          curDst = dr;
          accL = v;
        } else {
          accL += v;
        }
      }
    }

    // ---- rotate pipeline ----
    tC = tN; tN += 1;
    if (tC >= tE) break;
    Rs0 = Ns0; Rs1 = Ns1; Rd0 = Nd0; Rd1 = Nd1;
    Re0 = Ne0; Re1 = Ne1; Re2 = Ne2;
    bR = bN; eR = eN; dR = dN;
  }

  // final flush
  if (lane < 32 && curDst >= 0)
    unsafeAtomicAdd(out_nm + (long)curDst * 32 + lane, accL);
}

extern "C" void kernel_launch(void* const* d_in, const int* in_sizes, int n_in,
                              void* d_out, int out_size, void* d_ws, size_t ws_size,
                              hipStream_t stream) {
  const float* x_node = (const float*)d_in[0];
  const float* x_edge = (const float*)d_in[1];
  const int*   src    = (const int*)d_in[2];
  const int*   dst    = (const int*)d_in[3];
  const int*   bm     = (const int*)d_in[4];
  const float* Wn1 = (const float*)d_in[5];  const float* bn1 = (const float*)d_in[6];
  const float* Wn2 = (const float*)d_in[7];  const float* bn2 = (const float*)d_in[8];
  const float* We1 = (const float*)d_in[9];  const float* be1 = (const float*)d_in[10];
  const float* We2 = (const float*)d_in[11]; const float* be2 = (const float*)d_in[12];
  float* out_nm = (float*)d_out;
  float* out_em = out_nm + (size_t)NN * 32;

  // workspace carve-up (ints): counts | loff | blocksum | blockpref | cursor | sorted
  int* ws        = (int*)d_ws;
  int* counts    = ws;                 // [0, 100000)
  int* loff      = ws + 100000;        // [100000, 200000)
  int* blocksum  = ws + 200000;        // [200000, 200512)
  int* blockpref = ws + 200512;        // [200512, 201024)
  int* cursor    = ws + 201024;        // [201024, 301024)
  int* sorted    = ws + 301024;        // [301024, 301024+NE)  ~14 MB total

  hipMemsetAsync(counts, 0, (size_t)NN * sizeof(int), stream);
  hipMemsetAsync(out_nm, 0, (size_t)NN * 32 * sizeof(float), stream);

  k_hist<<<(NE + 255) / 256, 256, 0, stream>>>(dst, counts);
  k_scan1<<<NBLK_SCAN, 256, 0, stream>>>(counts, loff, blocksum);
  k_scan2<<<1, 512, 0, stream>>>(blocksum, blockpref);
  k_scan3<<<NBLK_SCAN, 256, 0, stream>>>(loff, blockpref, cursor);
  k_scatter<<<(NE + 255) / 256, 256, 0, stream>>>(dst, cursor, sorted);

  mpn_main<<<2048, 256, 0, stream>>>(x_node, x_edge, src, dst, bm, sorted,
                                     Wn1, bn1, Wn2, bn2, We1, be1, We2, be2,
                                     out_nm, out_em);
}

// Round 6
// 362.833 us; speedup vs baseline: 2.3868x; 2.3868x over previous
//
#include <hip/hip_runtime.h>
#include <hip/hip_bf16.h>

typedef __attribute__((ext_vector_type(8))) short short8;
typedef __attribute__((ext_vector_type(4))) short s16x4;
typedef __attribute__((ext_vector_type(4))) int   int4v;
typedef __attribute__((ext_vector_type(4))) float f32x4;
typedef __attribute__((ext_vector_type(2))) float f32x2;

#define NN 100000
#define NE 3200000
#define NTILES (NE / 16)

__device__ __forceinline__ short f2bf(float f) {
  __hip_bfloat16 h = __float2bfloat16(f);
  return *reinterpret_cast<short*>(&h);
}

__device__ __forceinline__ f32x4 mfma16(short8 a, short8 b, f32x4 c) {
  return __builtin_amdgcn_mfma_f32_16x16x32_bf16(a, b, c, 0, 0, 0);
}

// Per-wave tile: 16 edges. A-frag: lane holds row (l&15), k=(l>>4)*8+j.
// B-frag: lane holds col (l&15). D: row=(l>>4)*4+r, col=(l&15).
// All global accesses are line-minimal: x_node rows gathered cooperatively
// (8 lanes x 16B per 128B row -> each unique cache line touched once),
// x_edge / em moved as single packed 384B transfers; fragment layouts are
// produced by per-wave LDS redistribution (LDS is otherwise idle).
__global__ void __launch_bounds__(256) mpn_main(
    const float* __restrict__ x_node,
    const float* __restrict__ x_edge,
    const int*   __restrict__ srcp,
    const int*   __restrict__ dstp,
    const int*   __restrict__ bmp,
    const float* __restrict__ Wn1, const float* __restrict__ bn1,
    const float* __restrict__ Wn2, const float* __restrict__ bn2,
    const float* __restrict__ We1, const float* __restrict__ be1,
    const float* __restrict__ We2, const float* __restrict__ be2,
    float* __restrict__ out_nm,
    float* __restrict__ out_em)
{
  // per-wave private tiles (no cross-wave sharing -> no barriers; in-wave
  // LDS RAW ordering is program-order within the wave)
  __shared__ short lds_x[4][32 * 40];   // rows 0-15 src, 16-31 dst; stride 40 shorts (80B, 16B-aligned frags, <=2-way banks)
  __shared__ short lds_xe[4][104];      // 96 bf16 edge feats (16 edges x 6)
  __shared__ short lds_h1[4][16][40];   // h1 transpose tile
  __shared__ float lds_emf[4][96];      // em tile, flat 16x6 f32
  __shared__ short lds_h2[4][16][72];   // h2 transpose tile

  const int tid  = threadIdx.x;
  const int wid  = tid >> 6;
  const int lane = tid & 63;
  const int col  = lane & 15;
  const int kg   = lane >> 4;
  const int srow   = lane >> 3;   // staging: 8 lanes per row
  const int schunk = lane & 7;    // 16B chunk within 128B row

  // ---- resident bf16 weight B-fragments (one-time) ----
  auto ldb = [&](const float* W, int K, int N, int kc, int nt) {
    int n  = nt * 16 + col;
    int k0 = kc * 32 + kg * 8;
    short8 r;
#pragma unroll
    for (int j = 0; j < 8; ++j) {
      int k = k0 + j;
      float v = (k < K && n < N) ? W[k * N + n] : 0.f;
      r[j] = f2bf(v);
    }
    return r;
  };

  short8 B_e1[3][2], B_n1[2][4], B_n2[2][2], B_e2;
#pragma unroll
  for (int kc = 0; kc < 3; ++kc)
#pragma unroll
    for (int nt = 0; nt < 2; ++nt) B_e1[kc][nt] = ldb(We1, 70, 32, kc, nt);
  B_e2 = ldb(We2, 32, 6, 0, 0);
#pragma unroll
  for (int kc = 0; kc < 2; ++kc)
#pragma unroll
    for (int nt = 0; nt < 4; ++nt) B_n1[kc][nt] = ldb(Wn1, 38, 64, kc, nt);
#pragma unroll
  for (int kc = 0; kc < 2; ++kc)
#pragma unroll
    for (int nt = 0; nt < 2; ++nt) B_n2[kc][nt] = ldb(Wn2, 64, 32, kc, nt);

  float bias_e1[2], bias_n1[4], bias_n2[2], bias_e2;
  bias_e1[0] = be1[col];      bias_e1[1] = be1[16 + col];
  bias_e2    = (col < 6) ? be2[col] : 0.f;
#pragma unroll
  for (int nt = 0; nt < 4; ++nt) bias_n1[nt] = bn1[nt * 16 + col];
  bias_n2[0] = bn2[col];      bias_n2[1] = bn2[16 + col];

  const int gw = blockIdx.x * 4 + wid;
  const int nw = gridDim.x * 4;

  for (int t = gw; t < NTILES; t += nw) {
    const int eb = t * 16;
    const int e  = eb + col;
    const int s  = srcp[e];          // 1 line
    const int d  = dstp[e];          // 1 line
    const bool back = bmp[e] != 0;   // 1 line

    // ---- cooperative, fully-coalesced x_node gather ----
    // rows for this lane's staging duty (values live in lanes 0..15)
    const int sA = __shfl(s, srow);        // src rows 0-7
    const int sB = __shfl(s, 8 + srow);    // src rows 8-15
    const int dA = __shfl(d, srow);
    const int dB = __shfl(d, 8 + srow);
    f32x4 vA = *(const f32x4*)(x_node + (long)sA * 32 + schunk * 4);
    f32x4 vB = *(const f32x4*)(x_node + (long)sB * 32 + schunk * 4);
    f32x4 vC = *(const f32x4*)(x_node + (long)dA * 32 + schunk * 4);
    f32x4 vD = *(const f32x4*)(x_node + (long)dB * 32 + schunk * 4);
    // edge feats: one packed 384B load (lanes 0-23)
    f32x4 vE;
    if (lane < 24) vE = *(const f32x4*)(x_edge + (long)eb * 6 + lane * 4);

    auto st4 = [&](int row, f32x4 v) {
      s16x4 p;
      p[0] = f2bf(v[0]); p[1] = f2bf(v[1]); p[2] = f2bf(v[2]); p[3] = f2bf(v[3]);
      *(s16x4*)&lds_x[wid][row * 40 + schunk * 4] = p;
    };
    st4(srow, vA); st4(8 + srow, vB); st4(16 + srow, vC); st4(24 + srow, vD);
    if (lane < 24) {
      s16x4 p;
      p[0] = f2bf(vE[0]); p[1] = f2bf(vE[1]); p[2] = f2bf(vE[2]); p[3] = f2bf(vE[3]);
      *(s16x4*)&lds_xe[wid][lane * 4] = p;
    }

    // ---- fragments from LDS ----
    short8 XS = *(const short8*)&lds_x[wid][col * 40 + kg * 8];
    short8 XD = *(const short8*)&lds_x[wid][(16 + col) * 40 + kg * 8];
    short8 AE = {0, 0, 0, 0, 0, 0, 0, 0};
    if (kg == 0) {
      int4v u = { *(const int*)&lds_xe[wid][col * 6],
                  *(const int*)&lds_xe[wid][col * 6 + 2],
                  *(const int*)&lds_xe[wid][col * 6 + 4], 0 };
      AE = __builtin_bit_cast(short8, u);
    }
    short8 Aa = back ? XD : XS;
    short8 Ab = back ? XS : XD;

    // ---- edge MLP layer 1 ----
    f32x4 a0 = {bias_e1[0], bias_e1[0], bias_e1[0], bias_e1[0]};
    f32x4 a1 = {bias_e1[1], bias_e1[1], bias_e1[1], bias_e1[1]};
    a0 = mfma16(Aa, B_e1[0][0], a0);
    a0 = mfma16(Ab, B_e1[1][0], a0);
    a0 = mfma16(AE, B_e1[2][0], a0);
    a1 = mfma16(Aa, B_e1[0][1], a1);
    a1 = mfma16(Ab, B_e1[1][1], a1);
    a1 = mfma16(AE, B_e1[2][1], a1);

#pragma unroll
    for (int r = 0; r < 4; ++r) {
      lds_h1[wid][kg * 4 + r][col]      = f2bf(fmaxf(a0[r], 0.f));
      lds_h1[wid][kg * 4 + r][16 + col] = f2bf(fmaxf(a1[r], 0.f));
    }
    short8 Ah1 = *(const short8*)&lds_h1[wid][col][kg * 8];

    // ---- edge MLP layer 2 ----
    f32x4 ae2 = {bias_e2, bias_e2, bias_e2, bias_e2};
    ae2 = mfma16(Ah1, B_e2, ae2);

    if (col < 6) {
#pragma unroll
      for (int r = 0; r < 4; ++r)
        lds_emf[wid][(kg * 4 + r) * 6 + col] = ae2[r];
    }
    short8 Aem = {0, 0, 0, 0, 0, 0, 0, 0};
    if (kg == 0) {
      f32x2 u0 = *(const f32x2*)&lds_emf[wid][col * 6];
      f32x2 u1 = *(const f32x2*)&lds_emf[wid][col * 6 + 2];
      f32x2 u2 = *(const f32x2*)&lds_emf[wid][col * 6 + 4];
      Aem[0] = f2bf(u0[0]); Aem[1] = f2bf(u0[1]);
      Aem[2] = f2bf(u1[0]); Aem[3] = f2bf(u1[1]);
      Aem[4] = f2bf(u2[0]); Aem[5] = f2bf(u2[1]);
    }
    // em flush: one packed 384B store (lanes 0-23)
    if (lane < 24) {
      f32x4 w = *(const f32x4*)&lds_emf[wid][lane * 4];
      *(f32x4*)(out_em + (long)eb * 6 + lane * 4) = w;
    }

    // ---- node MLP layer 1 ----
    f32x4 an[4];
#pragma unroll
    for (int nt = 0; nt < 4; ++nt) {
      an[nt] = (f32x4){bias_n1[nt], bias_n1[nt], bias_n1[nt], bias_n1[nt]};
      an[nt] = mfma16(XD,  B_n1[0][nt], an[nt]);
      an[nt] = mfma16(Aem, B_n1[1][nt], an[nt]);
    }
#pragma unroll
    for (int nt = 0; nt < 4; ++nt)
#pragma unroll
      for (int r = 0; r < 4; ++r)
        lds_h2[wid][kg * 4 + r][nt * 16 + col] = f2bf(fmaxf(an[nt][r], 0.f));
    short8 Ah2a = *(const short8*)&lds_h2[wid][col][kg * 8];
    short8 Ah2b = *(const short8*)&lds_h2[wid][col][32 + kg * 8];

    // ---- node MLP layer 2 ----
    f32x4 am0 = {bias_n2[0], bias_n2[0], bias_n2[0], bias_n2[0]};
    f32x4 am1 = {bias_n2[1], bias_n2[1], bias_n2[1], bias_n2[1]};
    am0 = mfma16(Ah2a, B_n2[0][0], am0);
    am0 = mfma16(Ah2b, B_n2[1][0], am0);
    am1 = mfma16(Ah2a, B_n2[0][1], am1);
    am1 = mfma16(Ah2b, B_n2[1][1], am1);

    // ---- scatter-add (dst ids via shuffle, no reload) ----
#pragma unroll
    for (int r = 0; r < 4; ++r) {
      int de = __shfl(d, kg * 4 + r);
      float* basep = out_nm + (long)de * 32 + col;
      unsafeAtomicAdd(basep,      am0[r]);
      unsafeAtomicAdd(basep + 16, am1[r]);
    }
  }
}

extern "C" void kernel_launch(void* const* d_in, const int* in_sizes, int n_in,
                              void* d_out, int out_size, void* d_ws, size_t ws_size,
                              hipStream_t stream) {
  const float* x_node = (const float*)d_in[0];
  const float* x_edge = (const float*)d_in[1];
  const int*   src    = (const int*)d_in[2];
  const int*   dst    = (const int*)d_in[3];
  const int*   bm     = (const int*)d_in[4];
  const float* Wn1 = (const float*)d_in[5];  const float* bn1 = (const float*)d_in[6];
  const float* Wn2 = (const float*)d_in[7];  const float* bn2 = (const float*)d_in[8];
  const float* We1 = (const float*)d_in[9];  const float* be1 = (const float*)d_in[10];
  const float* We2 = (const float*)d_in[11]; const float* be2 = (const float*)d_in[12];
  float* out_nm = (float*)d_out;
  float* out_em = out_nm + (size_t)NN * 32;

  hipMemsetAsync(out_nm, 0, (size_t)NN * 32 * sizeof(float), stream);
  mpn_main<<<2048, 256, 0, stream>>>(x_node, x_edge, src, dst, bm,
                                     Wn1, bn1, Wn2, bn2, We1, be1, We2, be2,
                                     out_nm, out_em);
}